// Round 1
// baseline (2062.500 us; speedup 1.0000x reference)
//
#include <hip/hip_runtime.h>

#define NN 100000
#define NE 3200000
#define IC 128
#define HD 64
#define BN_EPS 1e-5f

// ---------------------------------------------------------------------------
// Input projection: pre[i][c] = sum_k x[i][k] * Wp[k][c] + bp[c]
// 4 rows per 256-thread block; Wp (32KB) staged in LDS.
__global__ __launch_bounds__(256) void k_gemm_in(
    const float* __restrict__ x, const float* __restrict__ Wp,
    const float* __restrict__ bp, float* __restrict__ pre) {
  __shared__ float sW[IC * HD];   // 32 KB
  __shared__ float sX[4 * IC];    // 2 KB
  int tid = threadIdx.x;
  for (int i = tid; i < IC * HD; i += 256) sW[i] = Wp[i];
  int row0 = blockIdx.x * 4;
  for (int i = tid; i < 4 * IC; i += 256) sX[i] = x[(size_t)row0 * IC + i];
  __syncthreads();
  int r = tid >> 6, c = tid & 63;
  float acc = bp[c];
  const float* xr = &sX[r * IC];
#pragma unroll 8
  for (int k = 0; k < IC; ++k) acc = fmaf(xr[k], sW[k * HD + c], acc);
  pre[(size_t)(row0 + r) * HD + c] = acc;
}

// ---------------------------------------------------------------------------
// BN stats: per-channel sum and sum-of-squares, atomically accumulated into
// stats[0..63] = sum, stats[64..127] = sumsq. stats must be pre-zeroed.
__global__ __launch_bounds__(256) void k_bn_stats(
    const float* __restrict__ pre, float* __restrict__ stats) {
  __shared__ float ss[256], sq[256];
  int tid = threadIdx.x;
  float s = 0.f, q = 0.f;
  for (size_t i = (size_t)blockIdx.x * 256 + tid; i < (size_t)NN * HD;
       i += (size_t)gridDim.x * 256) {
    float v = pre[i];
    s += v;
    q = fmaf(v, v, q);
  }
  ss[tid] = s;
  sq[tid] = q;
  __syncthreads();
  if (tid < 64) {
    s = ss[tid] + ss[tid + 64] + ss[tid + 128] + ss[tid + 192];
    q = sq[tid] + sq[tid + 64] + sq[tid + 128] + sq[tid + 192];
    atomicAdd(&stats[tid], s);
    atomicAdd(&stats[64 + tid], q);
  }
}

// ---------------------------------------------------------------------------
// BN normalize + ReLU (+ optional residual added AFTER relu, per reference).
template <bool RESID>
__global__ __launch_bounds__(256) void k_bn_relu(
    const float* __restrict__ pre, const float* __restrict__ stats,
    const float* __restrict__ g, const float* __restrict__ b,
    const float* __restrict__ resid, float* __restrict__ out) {
  size_t i = (size_t)blockIdx.x * 256 + threadIdx.x;
  int c = threadIdx.x & 63;
  const float invN = 1.0f / NN;
  float m = stats[c] * invN;
  float v = stats[64 + c] * invN - m * m;
  float sc = g[c] * rsqrtf(v + BN_EPS);
  float val = (pre[i] - m) * sc + b[c];
  val = fmaxf(val, 0.f);
  if (RESID) val += resid[i];
  out[i] = val;
}

// ---------------------------------------------------------------------------
// Edge aggregation: one wave (64 lanes) per edge; lane = channel.
// summed[dst][c] += h[src][c]; cnt[dst] += 1.
__global__ __launch_bounds__(256) void k_aggr(
    const int* __restrict__ src, const int* __restrict__ dst,
    const float* __restrict__ h, float* __restrict__ summed,
    float* __restrict__ cnt) {
  int lane = threadIdx.x & 63;
  int wid = (int)((blockIdx.x * blockDim.x + threadIdx.x) >> 6);
  int nw = (int)((gridDim.x * blockDim.x) >> 6);
  for (int e = wid; e < NE; e += nw) {
    int s = src[e];
    int d = dst[e];
    float v = h[(size_t)s * HD + lane];
    atomicAdd(&summed[(size_t)d * HD + lane], v);
    if (lane == 0) atomicAdd(&cnt[d], 1.0f);
  }
}

// ---------------------------------------------------------------------------
// SAGE combine: pre[i] = (summed[i]/max(cnt,1)) @ Wl + bl + h[i] @ Wr
// 8 rows per 512-thread block; both 16KB weight mats staged in LDS.
__global__ __launch_bounds__(512) void k_combine(
    const float* __restrict__ summed, const float* __restrict__ cnt,
    const float* __restrict__ h, const float* __restrict__ Wl,
    const float* __restrict__ bl, const float* __restrict__ Wr,
    float* __restrict__ pre) {
  __shared__ float sWl[HD * HD], sWr[HD * HD];  // 16 KB each
  __shared__ float sA[8 * HD], sH[8 * HD];      // 2 KB each
  int tid = threadIdx.x;
  for (int i = tid; i < HD * HD; i += 512) {
    sWl[i] = Wl[i];
    sWr[i] = Wr[i];
  }
  int row0 = blockIdx.x * 8;
  for (int i = tid; i < 8 * HD; i += 512) {
    int row = row0 + (i >> 6);
    float ct = fmaxf(cnt[row], 1.0f);
    sA[i] = summed[(size_t)row0 * HD + i] / ct;
    sH[i] = h[(size_t)row0 * HD + i];
  }
  __syncthreads();
  int r = tid >> 6, c = tid & 63;
  float acc = bl[c];
  const float* ar = &sA[r * HD];
  const float* hr = &sH[r * HD];
#pragma unroll 8
  for (int k = 0; k < HD; ++k) {
    acc = fmaf(ar[k], sWl[k * HD + c], acc);
    acc = fmaf(hr[k], sWr[k * HD + c], acc);
  }
  pre[(size_t)(row0 + r) * HD + c] = acc;
}

// ---------------------------------------------------------------------------
// Output head: out[i][o] = sum_k h[i][k]*Wo[k][o] + bo[o], o in {0,1}.
// One wave per row, shuffle reduce.
__global__ __launch_bounds__(256) void k_head(
    const float* __restrict__ h, const float* __restrict__ Wo,
    const float* __restrict__ bo, float* __restrict__ out) {
  int lane = threadIdx.x & 63;
  int wid = (int)((blockIdx.x * blockDim.x + threadIdx.x) >> 6);
  int nw = (int)((gridDim.x * blockDim.x) >> 6);
  float w0 = Wo[lane * 2], w1 = Wo[lane * 2 + 1];
  float b0 = bo[0], b1 = bo[1];
  for (int row = wid; row < NN; row += nw) {
    float v = h[(size_t)row * HD + lane];
    float a0 = v * w0, a1 = v * w1;
#pragma unroll
    for (int off = 32; off > 0; off >>= 1) {
      a0 += __shfl_down(a0, off);
      a1 += __shfl_down(a1, off);
    }
    if (lane == 0) {
      out[(size_t)row * 2] = a0 + b0;
      out[(size_t)row * 2 + 1] = a1 + b1;
    }
  }
}

// ---------------------------------------------------------------------------
extern "C" void kernel_launch(void* const* d_in, const int* in_sizes, int n_in,
                              void* d_out, int out_size, void* d_ws,
                              size_t ws_size, hipStream_t stream) {
  const float* x = (const float*)d_in[0];
  const int* ei = (const int*)d_in[1];
  const float* Wp = (const float*)d_in[2];
  const float* bp = (const float*)d_in[3];
  const float* g_in = (const float*)d_in[4];
  const float* b_in = (const float*)d_in[5];
  const float* Wl0 = (const float*)d_in[6];
  const float* bl0 = (const float*)d_in[7];
  const float* Wr0 = (const float*)d_in[8];
  const float* g0 = (const float*)d_in[9];
  const float* b0 = (const float*)d_in[10];
  const float* Wl1 = (const float*)d_in[11];
  const float* bl1 = (const float*)d_in[12];
  const float* Wr1 = (const float*)d_in[13];
  const float* g1 = (const float*)d_in[14];
  const float* b1 = (const float*)d_in[15];
  const float* Wo = (const float*)d_in[16];
  const float* bo = (const float*)d_in[17];
  float* out = (float*)d_out;

  const int* src = ei;
  const int* dst = ei + NE;

  float* ws = (float*)d_ws;
  float* h0 = ws;                   // [NN*HD]
  float* pre = ws + (size_t)NN * HD;       // [NN*HD]
  float* hb = ws + (size_t)2 * NN * HD;    // [NN*HD]
  float* summed = ws + (size_t)3 * NN * HD;  // [NN*HD]
  float* cnt = ws + (size_t)4 * NN * HD;     // [NN]  (contiguous after summed)
  float* stats = cnt + NN;                   // [128]

  const int ELEM_BLOCKS = (NN * HD) / 256;   // 25000
  const int GEMM_BLOCKS = NN / 4;            // 25000
  const int COMB_BLOCKS = NN / 8;            // 12500

  // ---- input projection + BN + relu -> h0
  k_gemm_in<<<GEMM_BLOCKS, 256, 0, stream>>>(x, Wp, bp, pre);
  hipMemsetAsync(stats, 0, 128 * sizeof(float), stream);
  k_bn_stats<<<1024, 256, 0, stream>>>(pre, stats);
  k_bn_relu<false><<<ELEM_BLOCKS, 256, 0, stream>>>(pre, stats, g_in, b_in,
                                                    nullptr, h0);

  // ---- layer 0
  hipMemsetAsync(summed, 0, ((size_t)NN * HD + NN) * sizeof(float), stream);
  k_aggr<<<2048, 256, 0, stream>>>(src, dst, h0, summed, cnt);
  k_combine<<<COMB_BLOCKS, 512, 0, stream>>>(summed, cnt, h0, Wl0, bl0, Wr0,
                                             pre);
  hipMemsetAsync(stats, 0, 128 * sizeof(float), stream);
  k_bn_stats<<<1024, 256, 0, stream>>>(pre, stats);
  k_bn_relu<false><<<ELEM_BLOCKS, 256, 0, stream>>>(pre, stats, g0, b0,
                                                    nullptr, hb);  // hb = h1

  // ---- layer 1 (residual = h0, added after relu)
  hipMemsetAsync(summed, 0, ((size_t)NN * HD + NN) * sizeof(float), stream);
  k_aggr<<<2048, 256, 0, stream>>>(src, dst, hb, summed, cnt);
  k_combine<<<COMB_BLOCKS, 512, 0, stream>>>(summed, cnt, hb, Wl1, bl1, Wr1,
                                             pre);
  hipMemsetAsync(stats, 0, 128 * sizeof(float), stream);
  k_bn_stats<<<1024, 256, 0, stream>>>(pre, stats);
  k_bn_relu<true><<<ELEM_BLOCKS, 256, 0, stream>>>(pre, stats, g1, b1, h0,
                                                   hb);  // hb = h2

  // ---- output head
  k_head<<<1024, 256, 0, stream>>>(hb, Wo, bo, out);
}